// Round 5
// baseline (56.146 us; speedup 1.0000x reference)
//
#include <hip/hip_runtime.h>
#include <cfloat>

#define BS 64
#define C  1024
#define D  64
#define CT 64

typedef __attribute__((ext_vector_type(8))) short short8;
typedef __attribute__((ext_vector_type(4))) float f32x4;
typedef unsigned short ushort_t;
typedef unsigned int uint_t;

__device__ __forceinline__ ushort_t f2bf(float f) {
    uint_t u = __float_as_uint(f);
    u += 0x7fffu + ((u >> 16) & 1u);          // round-to-nearest-even
    return (ushort_t)(u >> 16);
}

// ---- prep: bf16 prototypes frag-ordered + zero part/cnt ----
// short8 idx = jt*128 + h*64 + ln;  jt=k>>4, h=K-half, ln=(k&15)+kslot*16
__global__ void prep_prot(const float* __restrict__ prot, ushort_t* __restrict__ ph,
                          float* __restrict__ part, int* __restrict__ cnt)
{
    if (blockIdx.x == 0) {
        if (threadIdx.x < 2 * BS) part[threadIdx.x] = 0.f;
        if (threadIdx.x == 0) *cnt = 0;
    }
    const int k = blockIdx.x * 128 + threadIdx.x;   // 0..1023
    const float4* row = (const float4*)(prot + (size_t)k * D);
    const int jt = k >> 4;
    #pragma unroll
    for (int dg = 0; dg < 8; dg++) {
        float4 a = row[dg * 2];
        float4 b = row[dg * 2 + 1];
        float x[8] = {a.x, a.y, a.z, a.w, b.x, b.y, b.z, b.w};
        short8 hv;
        #pragma unroll
        for (int e = 0; e < 8; e++) hv[e] = (short)f2bf(x[e]);
        const int h  = dg >> 2;
        const int ln = (k & 15) + (dg & 3) * 16;
        ((short8*)ph)[(size_t)jt * 128 + h * 64 + ln] = hv;
    }
}

// ---- main: raw-x MFMA argmax, fused finish ----
__global__ __launch_bounds__(256, 4)
void triplet_mfma(const float* __restrict__ inputs,
                  const float* __restrict__ label,
                  const float* __restrict__ prot,
                  const ushort_t* __restrict__ phg,
                  float* __restrict__ part, int* __restrict__ cnt,
                  float* __restrict__ out)
{
    __shared__ short8 xh[512];           // 8 KB raw-x frags (4 row-tiles x 2 halves x 64)
    __shared__ uint_t redk[CT][4];
    __shared__ float  wred[8];
    __shared__ int    isLastS;

    const int tid  = threadIdx.x;
    const int lane = tid & 63;
    const int wid  = tid >> 6;           // 0..3 = col-group
    const int b    = blockIdx.x >> 4;
    const int c0   = (blockIdx.x & 15) * CT;

    const short8* BH = (const short8*)phg;

    // issue first two B tiles immediately (covered by convert phase)
    short8 ta0 = BH[(size_t)(wid * 16 + 0) * 128 + lane];
    short8 ta1 = BH[(size_t)(wid * 16 + 0) * 128 + 64 + lane];
    short8 tb0 = BH[(size_t)(wid * 16 + 1) * 128 + lane];
    short8 tb1 = BH[(size_t)(wid * 16 + 1) * 128 + 64 + lane];

    // convert raw X -> frag-ordered bf16 (no normalization needed for argmax)
    #pragma unroll
    for (int it = 0; it < 2; it++) {
        int task = tid + it * 256;            // 0..511 = 64 rows x 8 dg
        int r = task >> 3, dg = task & 7;
        const float* src = inputs + (size_t)(b * C + c0 + r) * D + dg * 8;
        float4 a = *(const float4*)src;
        float4 bb = *(const float4*)(src + 4);
        float x[8] = {a.x, a.y, a.z, a.w, bb.x, bb.y, bb.z, bb.w};
        short8 hv;
        #pragma unroll
        for (int e = 0; e < 8; e++) hv[e] = (short)f2bf(x[e]);
        int f  = (r >> 4) * 2 + (dg >> 2);
        int ln = (r & 15) + (dg & 3) * 16;
        xh[f * 64 + ln] = hv;
    }
    __syncthreads();

    // A fragments: every wave covers all 64 rows (distinct col ranges)
    short8 ah[4][2];
    #pragma unroll
    for (int i = 0; i < 4; i++) {
        ah[i][0] = xh[(i * 2 + 0) * 64 + lane];
        ah[i][1] = xh[(i * 2 + 1) * 64 + lane];
    }

    uint_t bestk[16];
    #pragma unroll
    for (int q = 0; q < 16; q++) bestk[q] = 0u;

    const uint_t MMASK = 0xFFFFFC00u;
    const int rowtile0 = c0 >> 4;
    const int rsub = (lane >> 4) * 4;
    const int csub = lane & 15;

    auto process = [&](int jt, short8 b0, short8 b1) {
        const int jg = wid * 16 + jt;
        const uint_t cidx = (uint_t)(1023 - (jg * 16 + csub));
        #pragma unroll
        for (int i = 0; i < 4; i++) {
            f32x4 acc = {16.f, 16.f, 16.f, 16.f};   // S_raw+16 in [8,24] > 0: sortable bits
            acc = __builtin_amdgcn_mfma_f32_16x16x32_bf16(ah[i][0], b0, acc, 0, 0, 0);
            acc = __builtin_amdgcn_mfma_f32_16x16x32_bf16(ah[i][1], b1, acc, 0, 0, 0);
            const bool dtile = (rowtile0 + i) == jg;   // wave-uniform
            #pragma unroll
            for (int r = 0; r < 4; r++) {
                uint_t key = (__float_as_uint(acc[r]) & MMASK) | cidx;
                if (dtile && (rsub + r) == csub) key = 0u;   // mask diagonal
                bestk[i * 4 + r] = bestk[i * 4 + r] > key ? bestk[i * 4 + r] : key;
            }
        }
    };

    // 16 tiles per wave, 2-tile-deep register prefetch, no barriers
    for (int jt = 0; jt < 16; jt += 2) {
        const int p0 = (jt + 2 < 16) ? jt + 2 : 15;
        const int p1 = (jt + 3 < 16) ? jt + 3 : 15;
        short8 n0 = BH[(size_t)(wid * 16 + p0) * 128 + lane];
        short8 n1 = BH[(size_t)(wid * 16 + p0) * 128 + 64 + lane];
        process(jt, ta0, ta1);
        short8 m0 = BH[(size_t)(wid * 16 + p1) * 128 + lane];
        short8 m1 = BH[(size_t)(wid * 16 + p1) * 128 + 64 + lane];
        process(jt + 1, tb0, tb1);
        ta0 = n0; ta1 = n1; tb0 = m0; tb1 = m1;
    }

    // cross-lane max over the 16 col-lanes
    #pragma unroll
    for (int i = 0; i < 4; i++)
        #pragma unroll
        for (int r = 0; r < 4; r++) {
            uint_t v = bestk[i * 4 + r];
            #pragma unroll
            for (int off = 1; off < 16; off <<= 1) {
                uint_t ov = (uint_t)__shfl_xor((int)v, off);
                v = v > ov ? v : ov;
            }
            if (csub == 0) redk[i * 16 + rsub + r][wid] = v;
        }
    __syncthreads();

    // epilogue: 4 threads per row, exact fp32 norms + d_ap/d_an
    float num = 0.f, den = 0.f;
    {
        const int row = tid >> 2, p4 = tid & 3;
        uint_t kk = redk[row][p4];
        {
            uint_t o1 = (uint_t)__shfl_xor((int)kk, 1); kk = kk > o1 ? kk : o1;
            uint_t o2 = (uint_t)__shfl_xor((int)kk, 2); kk = kk > o2 ? kk : o2;
        }
        const int bi = 1023 - (int)(kk & 0x3FFu);
        const int cg = c0 + row;

        const float4* xr = (const float4*)(inputs + (size_t)(b * C + cg) * D) + p4 * 4;
        float4 xv[4];
        float x2 = 0.f;
        #pragma unroll
        for (int q = 0; q < 4; q++) {
            xv[q] = xr[q];
            x2 = fmaf(xv[q].x, xv[q].x, fmaf(xv[q].y, xv[q].y,
                 fmaf(xv[q].z, xv[q].z, fmaf(xv[q].w, xv[q].w, x2))));
        }
        x2 += __shfl_xor(x2, 1);
        x2 += __shfl_xor(x2, 2);
        const float inv = 1.0f / fmaxf(sqrtf(x2), 1e-12f);

        const float4* pp = (const float4*)(prot + (size_t)cg * D) + p4 * 4;
        const float4* pn = (const float4*)(prot + (size_t)bi * D) + p4 * 4;
        float sap = 0.f, san = 0.f;
        #pragma unroll
        for (int q = 0; q < 4; q++) {
            float4 aa = pp[q];
            float4 nn = pn[q];
            float t;
            t = fmaf(xv[q].x, inv, -aa.x) + 1e-6f;  sap = fmaf(t, t, sap);
            t = fmaf(xv[q].y, inv, -aa.y) + 1e-6f;  sap = fmaf(t, t, sap);
            t = fmaf(xv[q].z, inv, -aa.z) + 1e-6f;  sap = fmaf(t, t, sap);
            t = fmaf(xv[q].w, inv, -aa.w) + 1e-6f;  sap = fmaf(t, t, sap);
            t = fmaf(xv[q].x, inv, -nn.x) + 1e-6f;  san = fmaf(t, t, san);
            t = fmaf(xv[q].y, inv, -nn.y) + 1e-6f;  san = fmaf(t, t, san);
            t = fmaf(xv[q].z, inv, -nn.z) + 1e-6f;  san = fmaf(t, t, san);
            t = fmaf(xv[q].w, inv, -nn.w) + 1e-6f;  san = fmaf(t, t, san);
        }
        sap += __shfl_xor(sap, 1);  sap += __shfl_xor(sap, 2);
        san += __shfl_xor(san, 1);  san += __shfl_xor(san, 2);
        if (p4 == 0) {
            float tri = fmaxf(sqrtf(sap) - sqrtf(san) + 0.2f, 0.0f);
            float w   = label[b * C + cg];
            num = tri * w;
            den = w;
        }
    }

    // block reduce: wave shuffles + one barrier
    #pragma unroll
    for (int off = 1; off < 64; off <<= 1) {
        num += __shfl_xor(num, off);
        den += __shfl_xor(den, off);
    }
    if (lane == 0) { wred[wid * 2] = num; wred[wid * 2 + 1] = den; }
    __syncthreads();

    if (tid == 0) {
        atomicAdd(&part[b * 2 + 0], wred[0] + wred[2] + wred[4] + wred[6]);
        atomicAdd(&part[b * 2 + 1], wred[1] + wred[3] + wred[5] + wred[7]);
        __threadfence();
        int old = __hip_atomic_fetch_add(cnt, 1, __ATOMIC_ACQ_REL, __HIP_MEMORY_SCOPE_AGENT);
        isLastS = (old == (int)gridDim.x - 1) ? 1 : 0;
    }
    __syncthreads();

    // last block computes the final mean
    if (isLastS && tid < 64) {
        float n = __hip_atomic_load(&part[tid * 2 + 0], __ATOMIC_RELAXED, __HIP_MEMORY_SCOPE_AGENT);
        float d = __hip_atomic_load(&part[tid * 2 + 1], __ATOMIC_RELAXED, __HIP_MEMORY_SCOPE_AGENT);
        float v = n / d;
        #pragma unroll
        for (int off = 32; off > 0; off >>= 1) v += __shfl_down(v, off);
        if (tid == 0) out[0] = v * (1.0f / (float)BS);
    }
}

extern "C" void kernel_launch(void* const* d_in, const int* in_sizes, int n_in,
                              void* d_out, int out_size, void* d_ws, size_t ws_size,
                              hipStream_t stream)
{
    const float* inputs = (const float*)d_in[0];
    const float* label  = (const float*)d_in[1];
    const float* prot   = (const float*)d_in[2];
    float* out = (float*)d_out;

    ushort_t* phg  = (ushort_t*)d_ws;                 // 128 KB
    float*    part = (float*)(phg + (size_t)C * D);   // 512 B (64 x 2)
    int*      cnt  = (int*)(part + 2 * BS);

    prep_prot<<<dim3(C / 128), dim3(128), 0, stream>>>(prot, phg, part, cnt);
    triplet_mfma<<<dim3(BS * (C / CT)), dim3(256), 0, stream>>>(
        inputs, label, prot, phg, part, cnt, out);
}

// Round 6
// 40.148 us; speedup vs baseline: 1.3985x; 1.3985x over previous
//
#include <hip/hip_runtime.h>
#include <cfloat>

#define BS 64
#define C  1024
#define D  64
#define CT 128

typedef __attribute__((ext_vector_type(8))) short short8;
typedef __attribute__((ext_vector_type(4))) float f32x4;
typedef unsigned short ushort_t;
typedef unsigned int uint_t;

__device__ __forceinline__ ushort_t f2bf(float f) {
    uint_t u = __float_as_uint(f);
    u += 0x7fffu + ((u >> 16) & 1u);          // round-to-nearest-even
    return (ushort_t)(u >> 16);
}

// ---- prep: bf16 prototypes frag-ordered + zero part/cnt ----
// short8 idx = jt*128 + h*64 + ln;  jt=k>>4, h=K-half, ln=(k&15)+kslot*16
__global__ void prep_prot(const float* __restrict__ prot, ushort_t* __restrict__ ph,
                          float* __restrict__ part, int* __restrict__ cnt)
{
    if (blockIdx.x == 0) {
        if (threadIdx.x < 2 * BS) part[threadIdx.x] = 0.f;
        if (threadIdx.x == 0) *cnt = 0;
    }
    const int k = blockIdx.x * 128 + threadIdx.x;   // 0..1023
    const float4* row = (const float4*)(prot + (size_t)k * D);
    const int jt = k >> 4;
    #pragma unroll
    for (int dg = 0; dg < 8; dg++) {
        float4 a = row[dg * 2];
        float4 b = row[dg * 2 + 1];
        float x[8] = {a.x, a.y, a.z, a.w, b.x, b.y, b.z, b.w};
        short8 hv;
        #pragma unroll
        for (int e = 0; e < 8; e++) hv[e] = (short)f2bf(x[e]);
        const int h  = dg >> 2;
        const int ln = (k & 15) + (dg & 3) * 16;
        ((short8*)ph)[(size_t)jt * 128 + h * 64 + ln] = hv;
    }
}

// ---- main: R4 structure (8 waves, 2-deep prefetch) + raw-x argmax + fused finish ----
__global__ __launch_bounds__(512, 4)
void triplet_mfma(const float* __restrict__ inputs,
                  const float* __restrict__ label,
                  const float* __restrict__ prot,
                  const ushort_t* __restrict__ phg,
                  float* __restrict__ part, int* __restrict__ cnt,
                  float* __restrict__ out)
{
    __shared__ short8 xh[1024];          // 16 KB raw-x frags (8 row-tiles x 2 halves x 64)
    __shared__ uint_t redk[CT][4];
    __shared__ float  wred[16];
    __shared__ int    isLastS;

    const int tid  = threadIdx.x;
    const int lane = tid & 63;
    const int wid  = tid >> 6;     // 0..7
    const int wr   = wid >> 2;     // 0..1 -> 64 c-rows
    const int wc   = wid & 3;      // 0..3 -> 256 k-cols
    const int b    = blockIdx.x >> 3;
    const int c0   = (blockIdx.x & 7) * CT;

    const short8* BH = (const short8*)phg;

    // issue first two B tiles immediately (covered by convert phase)
    short8 ta0 = BH[(size_t)(wc * 16 + 0) * 128 + lane];
    short8 ta1 = BH[(size_t)(wc * 16 + 0) * 128 + 64 + lane];
    short8 tb0 = BH[(size_t)(wc * 16 + 1) * 128 + lane];
    short8 tb1 = BH[(size_t)(wc * 16 + 1) * 128 + 64 + lane];

    // convert raw X -> frag-ordered bf16 (no normalization: argmax(S_raw) is scale-invariant)
    #pragma unroll
    for (int it = 0; it < 2; it++) {
        int task = tid + it * 512;            // 0..1023 = 128 rows x 8 dg
        int r = task >> 3, dg = task & 7;
        const float* src = inputs + (size_t)(b * C + c0 + r) * D + dg * 8;
        float4 a = *(const float4*)src;
        float4 bb = *(const float4*)(src + 4);
        float x[8] = {a.x, a.y, a.z, a.w, bb.x, bb.y, bb.z, bb.w};
        short8 hv;
        #pragma unroll
        for (int e = 0; e < 8; e++) hv[e] = (short)f2bf(x[e]);
        int f  = (r >> 4) * 2 + (dg >> 2);
        int ln = (r & 15) + (dg & 3) * 16;
        xh[f * 64 + ln] = hv;
    }
    __syncthreads();

    // A fragments for this wave's 64 rows
    short8 ah[4][2];
    #pragma unroll
    for (int i = 0; i < 4; i++) {
        ah[i][0] = xh[((4 * wr + i) * 2 + 0) * 64 + lane];
        ah[i][1] = xh[((4 * wr + i) * 2 + 1) * 64 + lane];
    }

    uint_t bestk[16];
    #pragma unroll
    for (int q = 0; q < 16; q++) bestk[q] = 0u;

    const uint_t MMASK = 0xFFFFFC00u;
    const int rowtile0 = (c0 >> 4) + wr * 4;
    const int rsub = (lane >> 4) * 4;
    const int csub = lane & 15;

    auto process = [&](int jt, short8 b0, short8 b1) {
        const int jg = wc * 16 + jt;
        const uint_t cidx = (uint_t)(1023 - (jg * 16 + csub));
        #pragma unroll
        for (int i = 0; i < 4; i++) {
            f32x4 acc = {16.f, 16.f, 16.f, 16.f};   // S_raw+16 in [5,27] > 0: sortable bits
            acc = __builtin_amdgcn_mfma_f32_16x16x32_bf16(ah[i][0], b0, acc, 0, 0, 0);
            acc = __builtin_amdgcn_mfma_f32_16x16x32_bf16(ah[i][1], b1, acc, 0, 0, 0);
            const bool dtile = (rowtile0 + i) == jg;   // wave-uniform
            #pragma unroll
            for (int r = 0; r < 4; r++) {
                uint_t key = (__float_as_uint(acc[r]) & MMASK) | cidx;
                if (dtile && (rsub + r) == csub) key = 0u;   // mask diagonal
                bestk[i * 4 + r] = bestk[i * 4 + r] > key ? bestk[i * 4 + r] : key;
            }
        }
    };

    // 16 tiles per wave, 2-tile-deep register prefetch, no barriers
    for (int jt = 0; jt < 16; jt += 2) {
        const int p0 = (jt + 2 < 16) ? jt + 2 : 15;
        const int p1 = (jt + 3 < 16) ? jt + 3 : 15;
        short8 n0 = BH[(size_t)(wc * 16 + p0) * 128 + lane];
        short8 n1 = BH[(size_t)(wc * 16 + p0) * 128 + 64 + lane];
        process(jt, ta0, ta1);
        short8 m0 = BH[(size_t)(wc * 16 + p1) * 128 + lane];
        short8 m1 = BH[(size_t)(wc * 16 + p1) * 128 + 64 + lane];
        process(jt + 1, tb0, tb1);
        ta0 = n0; ta1 = n1; tb0 = m0; tb1 = m1;
    }

    // cross-lane max over the 16 col-lanes
    #pragma unroll
    for (int i = 0; i < 4; i++)
        #pragma unroll
        for (int r = 0; r < 4; r++) {
            uint_t v = bestk[i * 4 + r];
            #pragma unroll
            for (int off = 1; off < 16; off <<= 1) {
                uint_t ov = (uint_t)__shfl_xor((int)v, off);
                v = v > ov ? v : ov;
            }
            if (csub == 0) redk[wr * 64 + i * 16 + rsub + r][wc] = v;
        }
    __syncthreads();

    // epilogue: 4 threads per row (512 = 4 x 128), exact fp32 norms + d_ap/d_an
    float num = 0.f, den = 0.f;
    {
        const int row = tid >> 2, p4 = tid & 3;
        uint_t kk = redk[row][p4];
        {
            uint_t o1 = (uint_t)__shfl_xor((int)kk, 1); kk = kk > o1 ? kk : o1;
            uint_t o2 = (uint_t)__shfl_xor((int)kk, 2); kk = kk > o2 ? kk : o2;
        }
        const int bi = 1023 - (int)(kk & 0x3FFu);
        const int cg = c0 + row;

        const float4* xr = (const float4*)(inputs + (size_t)(b * C + cg) * D) + p4 * 4;
        float4 xv[4];
        float x2 = 0.f;
        #pragma unroll
        for (int q = 0; q < 4; q++) {
            xv[q] = xr[q];
            x2 = fmaf(xv[q].x, xv[q].x, fmaf(xv[q].y, xv[q].y,
                 fmaf(xv[q].z, xv[q].z, fmaf(xv[q].w, xv[q].w, x2))));
        }
        x2 += __shfl_xor(x2, 1);
        x2 += __shfl_xor(x2, 2);
        const float inv = 1.0f / fmaxf(sqrtf(x2), 1e-12f);

        const float4* pp = (const float4*)(prot + (size_t)cg * D) + p4 * 4;
        const float4* pn = (const float4*)(prot + (size_t)bi * D) + p4 * 4;
        float sap = 0.f, san = 0.f;
        #pragma unroll
        for (int q = 0; q < 4; q++) {
            float4 aa = pp[q];
            float4 nn = pn[q];
            float t;
            t = fmaf(xv[q].x, inv, -aa.x) + 1e-6f;  sap = fmaf(t, t, sap);
            t = fmaf(xv[q].y, inv, -aa.y) + 1e-6f;  sap = fmaf(t, t, sap);
            t = fmaf(xv[q].z, inv, -aa.z) + 1e-6f;  sap = fmaf(t, t, sap);
            t = fmaf(xv[q].w, inv, -aa.w) + 1e-6f;  sap = fmaf(t, t, sap);
            t = fmaf(xv[q].x, inv, -nn.x) + 1e-6f;  san = fmaf(t, t, san);
            t = fmaf(xv[q].y, inv, -nn.y) + 1e-6f;  san = fmaf(t, t, san);
            t = fmaf(xv[q].z, inv, -nn.z) + 1e-6f;  san = fmaf(t, t, san);
            t = fmaf(xv[q].w, inv, -nn.w) + 1e-6f;  san = fmaf(t, t, san);
        }
        sap += __shfl_xor(sap, 1);  sap += __shfl_xor(sap, 2);
        san += __shfl_xor(san, 1);  san += __shfl_xor(san, 2);
        if (p4 == 0) {
            float tri = fmaxf(sqrtf(sap) - sqrtf(san) + 0.2f, 0.0f);
            float w   = label[b * C + cg];
            num = tri * w;
            den = w;
        }
    }

    // block reduce: wave shuffles + one barrier
    #pragma unroll
    for (int off = 1; off < 64; off <<= 1) {
        num += __shfl_xor(num, off);
        den += __shfl_xor(den, off);
    }
    if (lane == 0) { wred[wid * 2] = num; wred[wid * 2 + 1] = den; }
    __syncthreads();

    if (tid == 0) {
        float sn = 0.f, sd = 0.f;
        #pragma unroll
        for (int wv = 0; wv < 8; wv++) { sn += wred[wv * 2]; sd += wred[wv * 2 + 1]; }
        atomicAdd(&part[b * 2 + 0], sn);
        atomicAdd(&part[b * 2 + 1], sd);
        __threadfence();
        int old = __hip_atomic_fetch_add(cnt, 1, __ATOMIC_ACQ_REL, __HIP_MEMORY_SCOPE_AGENT);
        isLastS = (old == (int)gridDim.x - 1) ? 1 : 0;
    }
    __syncthreads();

    // last block computes the final mean
    if (isLastS && tid < 64) {
        float n = __hip_atomic_load(&part[tid * 2 + 0], __ATOMIC_RELAXED, __HIP_MEMORY_SCOPE_AGENT);
        float d = __hip_atomic_load(&part[tid * 2 + 1], __ATOMIC_RELAXED, __HIP_MEMORY_SCOPE_AGENT);
        float v = n / d;
        #pragma unroll
        for (int off = 32; off > 0; off >>= 1) v += __shfl_down(v, off);
        if (tid == 0) out[0] = v * (1.0f / (float)BS);
    }
}

extern "C" void kernel_launch(void* const* d_in, const int* in_sizes, int n_in,
                              void* d_out, int out_size, void* d_ws, size_t ws_size,
                              hipStream_t stream)
{
    const float* inputs = (const float*)d_in[0];
    const float* label  = (const float*)d_in[1];
    const float* prot   = (const float*)d_in[2];
    float* out = (float*)d_out;

    ushort_t* phg  = (ushort_t*)d_ws;                 // 128 KB
    float*    part = (float*)(phg + (size_t)C * D);   // 512 B (64 x 2)
    int*      cnt  = (int*)(part + 2 * BS);

    prep_prot<<<dim3(C / 128), dim3(128), 0, stream>>>(prot, phg, part, cnt);
    triplet_mfma<<<dim3(BS * (C / CT)), dim3(512), 0, stream>>>(
        inputs, label, prot, phg, part, cnt, out);
}

// Round 7
// 39.736 us; speedup vs baseline: 1.4130x; 1.0104x over previous
//
#include <hip/hip_runtime.h>
#include <cfloat>

#define BS 64
#define C  1024
#define D  64
#define CT 128

typedef __attribute__((ext_vector_type(8))) short short8;
typedef __attribute__((ext_vector_type(4))) float f32x4;
typedef unsigned short ushort_t;
typedef unsigned int uint_t;

__device__ __forceinline__ ushort_t f2bf(float f) {
    uint_t u = __float_as_uint(f);
    u += 0x7fffu + ((u >> 16) & 1u);          // round-to-nearest-even
    return (ushort_t)(u >> 16);
}

// ---- prep: bf16 prototypes frag-ordered + zero part/cnt ----
// short8 idx = jt*128 + h*64 + ln;  jt=k>>4, h=K-half, ln=(k&15)+kslot*16
__global__ void prep_prot(const float* __restrict__ prot, ushort_t* __restrict__ ph,
                          float* __restrict__ part, int* __restrict__ cnt)
{
    if (blockIdx.x == 0) {
        if (threadIdx.x < 2 * BS) part[threadIdx.x] = 0.f;
        if (threadIdx.x == 0) *cnt = 0;
    }
    const int k = blockIdx.x * 128 + threadIdx.x;   // 0..1023
    const float4* row = (const float4*)(prot + (size_t)k * D);
    const int jt = k >> 4;
    #pragma unroll
    for (int dg = 0; dg < 8; dg++) {
        float4 a = row[dg * 2];
        float4 b = row[dg * 2 + 1];
        float x[8] = {a.x, a.y, a.z, a.w, b.x, b.y, b.z, b.w};
        short8 hv;
        #pragma unroll
        for (int e = 0; e < 8; e++) hv[e] = (short)f2bf(x[e]);
        const int h  = dg >> 2;
        const int ln = (k & 15) + (dg & 3) * 16;
        ((short8*)ph)[(size_t)jt * 128 + h * 64 + ln] = hv;
    }
}

// ---- main: 8 waves, 2-deep PINNED register prefetch, raw-x argmax, fused finish ----
__global__ __launch_bounds__(512, 4)
void triplet_mfma(const float* __restrict__ inputs,
                  const float* __restrict__ label,
                  const float* __restrict__ prot,
                  const ushort_t* __restrict__ phg,
                  float* __restrict__ part, int* __restrict__ cnt,
                  float* __restrict__ out)
{
    __shared__ short8 xh[1024];          // 16 KB raw-x frags (8 row-tiles x 2 halves x 64)
    __shared__ uint_t redk[CT][4];
    __shared__ float  wred[16];
    __shared__ int    isLastS;

    const int tid  = threadIdx.x;
    const int lane = tid & 63;
    const int wid  = tid >> 6;     // 0..7
    const int wr   = wid >> 2;     // 0..1 -> 64 c-rows
    const int wc   = wid & 3;      // 0..3 -> 256 k-cols
    const int b    = blockIdx.x >> 3;
    const int c0   = (blockIdx.x & 7) * CT;

    const short8* BH = (const short8*)phg;

    // issue first two B tiles immediately (covered by convert phase)
    short8 ta0 = BH[(size_t)(wc * 16 + 0) * 128 + lane];
    short8 ta1 = BH[(size_t)(wc * 16 + 0) * 128 + 64 + lane];
    short8 tb0 = BH[(size_t)(wc * 16 + 1) * 128 + lane];
    short8 tb1 = BH[(size_t)(wc * 16 + 1) * 128 + 64 + lane];

    // convert raw X -> frag-ordered bf16 (no normalization: argmax(S_raw) is scale-invariant)
    #pragma unroll
    for (int it = 0; it < 2; it++) {
        int task = tid + it * 512;            // 0..1023 = 128 rows x 8 dg
        int r = task >> 3, dg = task & 7;
        const float* src = inputs + (size_t)(b * C + c0 + r) * D + dg * 8;
        float4 a = *(const float4*)src;
        float4 bb = *(const float4*)(src + 4);
        float x[8] = {a.x, a.y, a.z, a.w, bb.x, bb.y, bb.z, bb.w};
        short8 hv;
        #pragma unroll
        for (int e = 0; e < 8; e++) hv[e] = (short)f2bf(x[e]);
        int f  = (r >> 4) * 2 + (dg >> 2);
        int ln = (r & 15) + (dg & 3) * 16;
        xh[f * 64 + ln] = hv;
    }
    __syncthreads();

    // A fragments for this wave's 64 rows
    short8 ah[4][2];
    #pragma unroll
    for (int i = 0; i < 4; i++) {
        ah[i][0] = xh[((4 * wr + i) * 2 + 0) * 64 + lane];
        ah[i][1] = xh[((4 * wr + i) * 2 + 1) * 64 + lane];
    }

    uint_t bestk[16];
    #pragma unroll
    for (int q = 0; q < 16; q++) bestk[q] = 0u;

    const uint_t MMASK = 0xFFFFFC00u;
    const int rowtile0 = (c0 >> 4) + wr * 4;
    const int rsub = (lane >> 4) * 4;
    const int csub = lane & 15;

    auto process = [&](int jt, short8 b0, short8 b1) {
        const int jg = wc * 16 + jt;
        const uint_t cidx = (uint_t)(1023 - (jg * 16 + csub));
        #pragma unroll
        for (int i = 0; i < 4; i++) {
            f32x4 acc = {16.f, 16.f, 16.f, 16.f};   // S_raw+16 in [5,27] > 0: sortable bits
            acc = __builtin_amdgcn_mfma_f32_16x16x32_bf16(ah[i][0], b0, acc, 0, 0, 0);
            acc = __builtin_amdgcn_mfma_f32_16x16x32_bf16(ah[i][1], b1, acc, 0, 0, 0);
            const bool dtile = (rowtile0 + i) == jg;   // wave-uniform
            #pragma unroll
            for (int r = 0; r < 4; r++) {
                uint_t key = (__float_as_uint(acc[r]) & MMASK) | cidx;
                if (dtile && (rsub + r) == csub) key = 0u;   // mask diagonal
                bestk[i * 4 + r] = bestk[i * 4 + r] > key ? bestk[i * 4 + r] : key;
            }
        }
    };

    // 16 tiles per wave, 2-tile-deep register prefetch, no barriers.
    // sched_barrier(0) pins each prefetch-load group ABOVE the following
    // MFMA/key block: without it the scheduler sinks the loads to their use
    // (VGPR 80->60, R5/R6 regression) and the pipeline becomes demand loads.
    for (int jt = 0; jt < 16; jt += 2) {
        const int p0 = (jt + 2 < 16) ? jt + 2 : 15;
        const int p1 = (jt + 3 < 16) ? jt + 3 : 15;
        short8 n0 = BH[(size_t)(wc * 16 + p0) * 128 + lane];
        short8 n1 = BH[(size_t)(wc * 16 + p0) * 128 + 64 + lane];
        __builtin_amdgcn_sched_barrier(0);
        process(jt, ta0, ta1);
        short8 m0 = BH[(size_t)(wc * 16 + p1) * 128 + lane];
        short8 m1 = BH[(size_t)(wc * 16 + p1) * 128 + 64 + lane];
        __builtin_amdgcn_sched_barrier(0);
        process(jt + 1, tb0, tb1);
        ta0 = n0; ta1 = n1; tb0 = m0; tb1 = m1;
    }

    // cross-lane max over the 16 col-lanes
    #pragma unroll
    for (int i = 0; i < 4; i++)
        #pragma unroll
        for (int r = 0; r < 4; r++) {
            uint_t v = bestk[i * 4 + r];
            #pragma unroll
            for (int off = 1; off < 16; off <<= 1) {
                uint_t ov = (uint_t)__shfl_xor((int)v, off);
                v = v > ov ? v : ov;
            }
            if (csub == 0) redk[wr * 64 + i * 16 + rsub + r][wc] = v;
        }
    __syncthreads();

    // epilogue: 4 threads per row (512 = 4 x 128), exact fp32 norms + d_ap/d_an
    float num = 0.f, den = 0.f;
    {
        const int row = tid >> 2, p4 = tid & 3;
        uint_t kk = redk[row][p4];
        {
            uint_t o1 = (uint_t)__shfl_xor((int)kk, 1); kk = kk > o1 ? kk : o1;
            uint_t o2 = (uint_t)__shfl_xor((int)kk, 2); kk = kk > o2 ? kk : o2;
        }
        const int bi = 1023 - (int)(kk & 0x3FFu);
        const int cg = c0 + row;

        const float4* xr = (const float4*)(inputs + (size_t)(b * C + cg) * D) + p4 * 4;
        float4 xv[4];
        float x2 = 0.f;
        #pragma unroll
        for (int q = 0; q < 4; q++) {
            xv[q] = xr[q];
            x2 = fmaf(xv[q].x, xv[q].x, fmaf(xv[q].y, xv[q].y,
                 fmaf(xv[q].z, xv[q].z, fmaf(xv[q].w, xv[q].w, x2))));
        }
        x2 += __shfl_xor(x2, 1);
        x2 += __shfl_xor(x2, 2);
        const float inv = 1.0f / fmaxf(sqrtf(x2), 1e-12f);

        const float4* pp = (const float4*)(prot + (size_t)cg * D) + p4 * 4;
        const float4* pn = (const float4*)(prot + (size_t)bi * D) + p4 * 4;
        float sap = 0.f, san = 0.f;
        #pragma unroll
        for (int q = 0; q < 4; q++) {
            float4 aa = pp[q];
            float4 nn = pn[q];
            float t;
            t = fmaf(xv[q].x, inv, -aa.x) + 1e-6f;  sap = fmaf(t, t, sap);
            t = fmaf(xv[q].y, inv, -aa.y) + 1e-6f;  sap = fmaf(t, t, sap);
            t = fmaf(xv[q].z, inv, -aa.z) + 1e-6f;  sap = fmaf(t, t, sap);
            t = fmaf(xv[q].w, inv, -aa.w) + 1e-6f;  sap = fmaf(t, t, sap);
            t = fmaf(xv[q].x, inv, -nn.x) + 1e-6f;  san = fmaf(t, t, san);
            t = fmaf(xv[q].y, inv, -nn.y) + 1e-6f;  san = fmaf(t, t, san);
            t = fmaf(xv[q].z, inv, -nn.z) + 1e-6f;  san = fmaf(t, t, san);
            t = fmaf(xv[q].w, inv, -nn.w) + 1e-6f;  san = fmaf(t, t, san);
        }
        sap += __shfl_xor(sap, 1);  sap += __shfl_xor(sap, 2);
        san += __shfl_xor(san, 1);  san += __shfl_xor(san, 2);
        if (p4 == 0) {
            float tri = fmaxf(sqrtf(sap) - sqrtf(san) + 0.2f, 0.0f);
            float w   = label[b * C + cg];
            num = tri * w;
            den = w;
        }
    }

    // block reduce: wave shuffles + one barrier
    #pragma unroll
    for (int off = 1; off < 64; off <<= 1) {
        num += __shfl_xor(num, off);
        den += __shfl_xor(den, off);
    }
    if (lane == 0) { wred[wid * 2] = num; wred[wid * 2 + 1] = den; }
    __syncthreads();

    if (tid == 0) {
        float sn = 0.f, sd = 0.f;
        #pragma unroll
        for (int wv = 0; wv < 8; wv++) { sn += wred[wv * 2]; sd += wred[wv * 2 + 1]; }
        atomicAdd(&part[b * 2 + 0], sn);
        atomicAdd(&part[b * 2 + 1], sd);
        __threadfence();
        int old = __hip_atomic_fetch_add(cnt, 1, __ATOMIC_ACQ_REL, __HIP_MEMORY_SCOPE_AGENT);
        isLastS = (old == (int)gridDim.x - 1) ? 1 : 0;
    }
    __syncthreads();

    // last block computes the final mean
    if (isLastS && tid < 64) {
        float n = __hip_atomic_load(&part[tid * 2 + 0], __ATOMIC_RELAXED, __HIP_MEMORY_SCOPE_AGENT);
        float d = __hip_atomic_load(&part[tid * 2 + 1], __ATOMIC_RELAXED, __HIP_MEMORY_SCOPE_AGENT);
        float v = n / d;
        #pragma unroll
        for (int off = 32; off > 0; off >>= 1) v += __shfl_down(v, off);
        if (tid == 0) out[0] = v * (1.0f / (float)BS);
    }
}

extern "C" void kernel_launch(void* const* d_in, const int* in_sizes, int n_in,
                              void* d_out, int out_size, void* d_ws, size_t ws_size,
                              hipStream_t stream)
{
    const float* inputs = (const float*)d_in[0];
    const float* label  = (const float*)d_in[1];
    const float* prot   = (const float*)d_in[2];
    float* out = (float*)d_out;

    ushort_t* phg  = (ushort_t*)d_ws;                 // 128 KB
    float*    part = (float*)(phg + (size_t)C * D);   // 512 B (64 x 2)
    int*      cnt  = (int*)(part + 2 * BS);

    prep_prot<<<dim3(C / 128), dim3(128), 0, stream>>>(prot, phg, part, cnt);
    triplet_mfma<<<dim3(BS * (C / CT)), dim3(512), 0, stream>>>(
        inputs, label, prot, phg, part, cnt, out);
}

// Round 8
// 30.383 us; speedup vs baseline: 1.8479x; 1.3078x over previous
//
#include <hip/hip_runtime.h>
#include <cfloat>

#define BS 64
#define C  1024
#define D  64
#define CT 128
#define NX8 (BS * C * D / 8)   // 524288 short8 X-fragments

typedef __attribute__((ext_vector_type(8))) short short8;
typedef __attribute__((ext_vector_type(4))) float f32x4;
typedef unsigned short ushort_t;
typedef unsigned int uint_t;

__device__ __forceinline__ ushort_t f2bf(float f) {
    uint_t u = __float_as_uint(f);
    u += 0x7fffu + ((u >> 16) & 1u);          // round-to-nearest-even
    return (ushort_t)(u >> 16);
}

// ---- prep: convert BOTH X and prot to bf16 frag-order in ws ----
// short8 out-index rel: ft=rel>>7, w=rel&127, h=w>>6, ln=w&63,
// row rr=ft*16+(ln&15), dg=h*4+(ln>>4). Stores fully coalesced; loads
// cover a dense 4KB window per wave.
__global__ __launch_bounds__(256)
void prep_cvt(const float* __restrict__ inputs, const float* __restrict__ prot,
              ushort_t* __restrict__ xhg, ushort_t* __restrict__ phg)
{
    const int idx = blockIdx.x * 256 + threadIdx.x;
    const bool isX = idx < NX8;
    const int rel = isX ? idx : idx - NX8;
    const float* sb = isX ? inputs : prot;
    ushort_t* db = isX ? xhg : phg;

    const int ft = rel >> 7, w = rel & 127, h = w >> 6, ln = w & 63;
    const int rr = ft * 16 + (ln & 15), dg = h * 4 + (ln >> 4);
    const float* s = sb + (size_t)rr * D + dg * 8;
    float4 a = *(const float4*)s;
    float4 b2 = *(const float4*)(s + 4);
    float x[8] = {a.x, a.y, a.z, a.w, b2.x, b2.y, b2.z, b2.w};
    short8 hv;
    #pragma unroll
    for (int e = 0; e < 8; e++) hv[e] = (short)f2bf(x[e]);
    ((short8*)db)[rel] = hv;
}

// ---- main: no convert phase, A-frags direct from global, pinned 2-deep prefetch ----
__global__ __launch_bounds__(512, 4)
void triplet_mfma(const float* __restrict__ inputs,
                  const float* __restrict__ label,
                  const float* __restrict__ prot,
                  const ushort_t* __restrict__ xhg,
                  const ushort_t* __restrict__ phg,
                  float* __restrict__ part)
{
    __shared__ uint_t redk[CT][4];
    __shared__ float  wred[16];

    const int tid  = threadIdx.x;
    const int lane = tid & 63;
    const int wid  = tid >> 6;     // 0..7
    const int wr   = wid >> 2;     // 0..1 -> 64 c-rows
    const int wc   = wid & 3;      // 0..3 -> 256 k-cols
    const int b    = blockIdx.x >> 3;
    const int c0   = (blockIdx.x & 7) * CT;

    const short8* BH = (const short8*)phg;
    const short8* XH = (const short8*)xhg;

    // issue first two B tiles immediately
    short8 ta0 = BH[(size_t)(wc * 16 + 0) * 128 + lane];
    short8 ta1 = BH[(size_t)(wc * 16 + 0) * 128 + 64 + lane];
    short8 tb0 = BH[(size_t)(wc * 16 + 1) * 128 + lane];
    short8 tb1 = BH[(size_t)(wc * 16 + 1) * 128 + 64 + lane];

    // A fragments for this wave's 64 rows, straight from pre-converted global
    const size_t ftb = (size_t)blockIdx.x * 8 + wr * 4;   // 16-row tile index
    short8 ah[4][2];
    #pragma unroll
    for (int i = 0; i < 4; i++) {
        ah[i][0] = XH[(ftb + i) * 128 + lane];
        ah[i][1] = XH[(ftb + i) * 128 + 64 + lane];
    }

    uint_t bestk[16];
    #pragma unroll
    for (int q = 0; q < 16; q++) bestk[q] = 0u;

    const uint_t MMASK = 0xFFFFFC00u;
    const int rowtile0 = (c0 >> 4) + wr * 4;
    const int rsub = (lane >> 4) * 4;
    const int csub = lane & 15;

    auto process = [&](int jt, short8 b0, short8 b1) {
        const int jg = wc * 16 + jt;
        const uint_t cidx = (uint_t)(1023 - (jg * 16 + csub));
        #pragma unroll
        for (int i = 0; i < 4; i++) {
            f32x4 acc = {16.f, 16.f, 16.f, 16.f};   // S_raw+16 in [4,28] > 0: sortable bits
            acc = __builtin_amdgcn_mfma_f32_16x16x32_bf16(ah[i][0], b0, acc, 0, 0, 0);
            acc = __builtin_amdgcn_mfma_f32_16x16x32_bf16(ah[i][1], b1, acc, 0, 0, 0);
            const bool dtile = (rowtile0 + i) == jg;   // wave-uniform
            #pragma unroll
            for (int r = 0; r < 4; r++) {
                uint_t key = (__float_as_uint(acc[r]) & MMASK) | cidx;
                if (dtile && (rsub + r) == csub) key = 0u;   // mask diagonal
                bestk[i * 4 + r] = bestk[i * 4 + r] > key ? bestk[i * 4 + r] : key;
            }
        }
    };

    // 16 tiles per wave, 2-tile-deep register prefetch, loads pinned above MFMA
    for (int jt = 0; jt < 16; jt += 2) {
        const int p0 = (jt + 2 < 16) ? jt + 2 : 15;
        const int p1 = (jt + 3 < 16) ? jt + 3 : 15;
        short8 n0 = BH[(size_t)(wc * 16 + p0) * 128 + lane];
        short8 n1 = BH[(size_t)(wc * 16 + p0) * 128 + 64 + lane];
        __builtin_amdgcn_sched_barrier(0);
        process(jt, ta0, ta1);
        short8 m0 = BH[(size_t)(wc * 16 + p1) * 128 + lane];
        short8 m1 = BH[(size_t)(wc * 16 + p1) * 128 + 64 + lane];
        __builtin_amdgcn_sched_barrier(0);
        process(jt + 1, tb0, tb1);
        ta0 = n0; ta1 = n1; tb0 = m0; tb1 = m1;
    }

    // cross-lane max over the 16 col-lanes
    #pragma unroll
    for (int i = 0; i < 4; i++)
        #pragma unroll
        for (int r = 0; r < 4; r++) {
            uint_t v = bestk[i * 4 + r];
            #pragma unroll
            for (int off = 1; off < 16; off <<= 1) {
                uint_t ov = (uint_t)__shfl_xor((int)v, off);
                v = v > ov ? v : ov;
            }
            if (csub == 0) redk[wr * 64 + i * 16 + rsub + r][wc] = v;
        }
    __syncthreads();

    // epilogue: 4 threads per row (512 = 4 x 128), exact fp32 norms + d_ap/d_an
    float num = 0.f, den = 0.f;
    {
        const int row = tid >> 2, p4 = tid & 3;
        uint_t kk = redk[row][p4];
        {
            uint_t o1 = (uint_t)__shfl_xor((int)kk, 1); kk = kk > o1 ? kk : o1;
            uint_t o2 = (uint_t)__shfl_xor((int)kk, 2); kk = kk > o2 ? kk : o2;
        }
        const int bi = 1023 - (int)(kk & 0x3FFu);
        const int cg = c0 + row;

        const float4* xr = (const float4*)(inputs + (size_t)(b * C + cg) * D) + p4 * 4;
        float4 xv[4];
        float x2 = 0.f;
        #pragma unroll
        for (int q = 0; q < 4; q++) {
            xv[q] = xr[q];
            x2 = fmaf(xv[q].x, xv[q].x, fmaf(xv[q].y, xv[q].y,
                 fmaf(xv[q].z, xv[q].z, fmaf(xv[q].w, xv[q].w, x2))));
        }
        x2 += __shfl_xor(x2, 1);
        x2 += __shfl_xor(x2, 2);
        const float inv = 1.0f / fmaxf(sqrtf(x2), 1e-12f);

        const float4* pp = (const float4*)(prot + (size_t)cg * D) + p4 * 4;
        const float4* pn = (const float4*)(prot + (size_t)bi * D) + p4 * 4;
        float sap = 0.f, san = 0.f;
        #pragma unroll
        for (int q = 0; q < 4; q++) {
            float4 aa = pp[q];
            float4 nn = pn[q];
            float t;
            t = fmaf(xv[q].x, inv, -aa.x) + 1e-6f;  sap = fmaf(t, t, sap);
            t = fmaf(xv[q].y, inv, -aa.y) + 1e-6f;  sap = fmaf(t, t, sap);
            t = fmaf(xv[q].z, inv, -aa.z) + 1e-6f;  sap = fmaf(t, t, sap);
            t = fmaf(xv[q].w, inv, -aa.w) + 1e-6f;  sap = fmaf(t, t, sap);
            t = fmaf(xv[q].x, inv, -nn.x) + 1e-6f;  san = fmaf(t, t, san);
            t = fmaf(xv[q].y, inv, -nn.y) + 1e-6f;  san = fmaf(t, t, san);
            t = fmaf(xv[q].z, inv, -nn.z) + 1e-6f;  san = fmaf(t, t, san);
            t = fmaf(xv[q].w, inv, -nn.w) + 1e-6f;  san = fmaf(t, t, san);
        }
        sap += __shfl_xor(sap, 1);  sap += __shfl_xor(sap, 2);
        san += __shfl_xor(san, 1);  san += __shfl_xor(san, 2);
        if (p4 == 0) {
            float tri = fmaxf(sqrtf(sap) - sqrtf(san) + 0.2f, 0.0f);
            float w   = label[b * C + cg];
            num = tri * w;
            den = w;
        }
    }

    // block reduce: wave shuffles + one barrier, plain per-block store
    #pragma unroll
    for (int off = 1; off < 64; off <<= 1) {
        num += __shfl_xor(num, off);
        den += __shfl_xor(den, off);
    }
    if (lane == 0) { wred[wid * 2] = num; wred[wid * 2 + 1] = den; }
    __syncthreads();

    if (tid == 0) {
        float sn = 0.f, sd = 0.f;
        #pragma unroll
        for (int wv = 0; wv < 8; wv++) { sn += wred[wv * 2]; sd += wred[wv * 2 + 1]; }
        part[blockIdx.x * 2 + 0] = sn;
        part[blockIdx.x * 2 + 1] = sd;
    }
}

__global__ void triplet_finish(const float* __restrict__ part, float* __restrict__ out)
{
    int t = threadIdx.x;  // 64 threads = 1 wave; t = batch index
    float num = 0.f, den = 0.f;
    #pragma unroll
    for (int h = 0; h < 8; h++) {
        num += part[(t * 8 + h) * 2 + 0];
        den += part[(t * 8 + h) * 2 + 1];
    }
    float v = num / den;
    #pragma unroll
    for (int off = 32; off > 0; off >>= 1) v += __shfl_down(v, off);
    if (t == 0) out[0] = v * (1.0f / (float)BS);
}

extern "C" void kernel_launch(void* const* d_in, const int* in_sizes, int n_in,
                              void* d_out, int out_size, void* d_ws, size_t ws_size,
                              hipStream_t stream)
{
    const float* inputs = (const float*)d_in[0];
    const float* label  = (const float*)d_in[1];
    const float* prot   = (const float*)d_in[2];
    float* out = (float*)d_out;

    ushort_t* xhg  = (ushort_t*)d_ws;                      // 8 MB
    ushort_t* phg  = xhg + (size_t)BS * C * D;             // 128 KB
    float*    part = (float*)(phg + (size_t)C * D);        // 4 KB

    prep_cvt<<<dim3((NX8 + C * D / 8) / 256), dim3(256), 0, stream>>>(
        inputs, prot, xhg, phg);
    triplet_mfma<<<dim3(BS * (C / CT)), dim3(512), 0, stream>>>(
        inputs, label, prot, xhg, phg, part);
    triplet_finish<<<1, 64, 0, stream>>>(part, out);
}